// Round 6
// baseline (244.358 us; speedup 1.0000x reference)
//
#include <hip/hip_runtime.h>
#include <hip/hip_bf16.h>
#include <stdint.h>

#define B_   4
#define T_   2048
#define H_   8
#define HD_  64
#define DM_  512
#define N3_  1536

typedef short bf_el;
typedef __attribute__((ext_vector_type(8))) bf_el bfrag;   // 8 bf16 = 4 VGPRs
typedef __attribute__((ext_vector_type(4))) float ffrag;

#define SCALE_L2E  0.18033688011112043f   /* 0.125 * log2(e) */
#define MASK_L2E   14426.950408889634f    /* 1e4  * log2(e) */

static __device__ __forceinline__ unsigned short f2bf(float f) {      // RNE
    union { float f; unsigned int i; } v; v.f = f;
    unsigned int r = v.i + 0x7fff + ((v.i >> 16) & 1);
    return (unsigned short)(r >> 16);
}
static __device__ __forceinline__ unsigned short f2bf_fast(float f) { // round-half-up
    union { float f; unsigned int i; } v; v.f = f;
    return (unsigned short)((v.i + 0x8000u) >> 16);
}

// ---------------------------------------------------------------------------
// Kernel 0: W fp32 [512,1536] -> Wt bf16 [1536,512]
// ---------------------------------------------------------------------------
__global__ __launch_bounds__(256) void k_transposeW(const float* __restrict__ W,
                                                    unsigned short* __restrict__ Wt) {
    __shared__ __align__(16) unsigned short Ls[64 * 72];
    const int n0 = blockIdx.x * 64;
    const int k0 = blockIdx.y * 64;
    const int tid = threadIdx.x;
#pragma unroll
    for (int i = 0; i < 4; ++i) {
        int chunk = tid + i * 256;   // 0..1023
        int k = chunk >> 4;          // 0..63
        int c = chunk & 15;          // 0..15 (float4 chunks)
        float4 f = *(const float4*)(W + (size_t)(k0 + k) * N3_ + n0 + c * 4);
        unsigned short* p = Ls + k * 72 + c * 4;
        p[0] = f2bf(f.x); p[1] = f2bf(f.y); p[2] = f2bf(f.z); p[3] = f2bf(f.w);
    }
    __syncthreads();
    const int n = tid >> 2;
    const int g = tid & 3;
    __align__(16) unsigned short tmp[16];
#pragma unroll
    for (int i = 0; i < 16; ++i) tmp[i] = Ls[(g * 16 + i) * 72 + n];
    uint4* dst = (uint4*)(Wt + (size_t)(n0 + n) * DM_ + k0 + g * 16);
    dst[0] = *(const uint4*)(tmp);
    dst[1] = *(const uint4*)(tmp + 8);
}

// ---------------------------------------------------------------------------
// Kernel 1: mask scan — one int flag per 64x64 mask tile (1 = has mask!=1).
// Reads the 64 MB mask exactly once; attn then skips all mask work on
// unmasked tiles (every tile, for the all-ones benchmark mask).
// grid: x = kv-tile (32), y = b*32 + q-tile (128)
// ---------------------------------------------------------------------------
__global__ __launch_bounds__(256) void k_maskscan(const float* __restrict__ mask,
                                                  int* __restrict__ flags) {
    __shared__ int wf[4];
    const int tid = threadIdx.x;
    const int wave = tid >> 6, lane = tid & 63;
    const int y = blockIdx.y;            // b*32 + qt
    const int b = y >> 5, qt = y & 31;
    const int kt = blockIdx.x;
    const int mr = tid >> 2;             // 0..63
    const int mc = tid & 3;              // 16-float chunk
    const float* mp = mask + ((size_t)b * T_ + qt * 64 + mr) * T_ + kt * 64 + mc * 16;
    bool any = false;
#pragma unroll
    for (int j = 0; j < 4; ++j) {
        float4 f = *(const float4*)(mp + j * 4);
        any = any | (f.x != 1.f) | (f.y != 1.f) | (f.z != 1.f) | (f.w != 1.f);
    }
    unsigned long long bal = __ballot(any);
    if (lane == 0) wf[wave] = (bal != 0ULL);
    __syncthreads();
    if (tid == 0) flags[y * 32 + kt] = wf[0] | wf[1] | wf[2] | wf[3];
}

// ---------------------------------------------------------------------------
// Kernel 2: X fp32 [8192,512] @ Wt^T + bias -> Q/K/Vt (bf16)
// Tile 128(m) x 192(n) = one head per block. Register-prefetch pipeline:
// global loads for kt+1 issued before the MFMA block of kt.
// ---------------------------------------------------------------------------
__global__ __launch_bounds__(256) void k_gemm_qkv(const float* __restrict__ X,
                                                  const unsigned short* __restrict__ Wt,
                                                  const float* __restrict__ bias,
                                                  unsigned short* __restrict__ Qb,
                                                  unsigned short* __restrict__ Kb,
                                                  unsigned short* __restrict__ Vtb) {
    // union: staging As[128*40](5120) + Bs[192*40](7680) == epilogue Cs[64*200](12800)
    __shared__ __align__(16) unsigned short SH[12800];
    unsigned short* As = SH;            // row stride 40 shorts (32 data + 8 pad)
    unsigned short* Bs = SH + 5120;
    unsigned short* Cs = SH;            // row stride 200 shorts (192 data + 8 pad)

    const int tid  = threadIdx.x;
    const int wave = tid >> 6;
    const int lane = tid & 63;
    const int quad = lane >> 4;
    const int l16  = lane & 15;
    const int wm = wave >> 1, wn = wave & 1;    // 2x2 waves: 64 rows x 96 cols each
    const int m0 = blockIdx.y * 128;
    const int h  = blockIdx.x;                  // head
    const int n0 = h * 192;

    float bvv[6];
#pragma unroll
    for (int ni = 0; ni < 6; ++ni) bvv[ni] = bias[n0 + wn * 96 + ni * 16 + l16];

    ffrag acc[4][6];
#pragma unroll
    for (int i = 0; i < 4; ++i)
#pragma unroll
        for (int j = 0; j < 6; ++j) acc[i][j] = (ffrag){0.f, 0.f, 0.f, 0.f};

    // per-thread staging assignments (fixed across kt)
    const int ar0 = tid >> 2,            ac0 = tid & 3;          // A chunk 0
    const int ar1 = (tid + 256) >> 2,    ac1 = tid & 3;          // A chunk 1
    float4 pa[4];
    uint4  pb[3];
    const int br[3] = { tid >> 2, (tid + 256) >> 2, (tid + 512) >> 2 };
    const int bc    = tid & 3;

    // preload kt = 0
    {
        const float* xp0 = X + (size_t)(m0 + ar0) * DM_ + ac0 * 8;
        const float* xp1 = X + (size_t)(m0 + ar1) * DM_ + ac1 * 8;
        pa[0] = *(const float4*)xp0; pa[1] = *(const float4*)(xp0 + 4);
        pa[2] = *(const float4*)xp1; pa[3] = *(const float4*)(xp1 + 4);
#pragma unroll
        for (int i = 0; i < 3; ++i)
            pb[i] = *(const uint4*)(Wt + (size_t)(n0 + br[i]) * DM_ + bc * 8);
    }

    for (int kt = 0; kt < 16; ++kt) {
        __syncthreads();
        // write staged regs -> LDS (A converts fp32->bf16)
        {
            __align__(16) unsigned short t8[8];
            t8[0] = f2bf_fast(pa[0].x); t8[1] = f2bf_fast(pa[0].y);
            t8[2] = f2bf_fast(pa[0].z); t8[3] = f2bf_fast(pa[0].w);
            t8[4] = f2bf_fast(pa[1].x); t8[5] = f2bf_fast(pa[1].y);
            t8[6] = f2bf_fast(pa[1].z); t8[7] = f2bf_fast(pa[1].w);
            *(uint4*)(As + ar0 * 40 + ac0 * 8) = *(const uint4*)t8;
            t8[0] = f2bf_fast(pa[2].x); t8[1] = f2bf_fast(pa[2].y);
            t8[2] = f2bf_fast(pa[2].z); t8[3] = f2bf_fast(pa[2].w);
            t8[4] = f2bf_fast(pa[3].x); t8[5] = f2bf_fast(pa[3].y);
            t8[6] = f2bf_fast(pa[3].z); t8[7] = f2bf_fast(pa[3].w);
            *(uint4*)(As + ar1 * 40 + ac1 * 8) = *(const uint4*)t8;
#pragma unroll
            for (int i = 0; i < 3; ++i)
                *(uint4*)(Bs + br[i] * 40 + bc * 8) = pb[i];
        }
        __syncthreads();
        // prefetch kt+1
        if (kt < 15) {
            const float* xp0 = X + (size_t)(m0 + ar0) * DM_ + (kt + 1) * 32 + ac0 * 8;
            const float* xp1 = X + (size_t)(m0 + ar1) * DM_ + (kt + 1) * 32 + ac1 * 8;
            pa[0] = *(const float4*)xp0; pa[1] = *(const float4*)(xp0 + 4);
            pa[2] = *(const float4*)xp1; pa[3] = *(const float4*)(xp1 + 4);
#pragma unroll
            for (int i = 0; i < 3; ++i)
                pb[i] = *(const uint4*)(Wt + (size_t)(n0 + br[i]) * DM_ + (kt + 1) * 32 + bc * 8);
        }
        bfrag af[4], bfr[6];
#pragma unroll
        for (int mi = 0; mi < 4; ++mi)
            af[mi] = *(const bfrag*)(As + (wm * 64 + mi * 16 + l16) * 40 + quad * 8);
#pragma unroll
        for (int ni = 0; ni < 6; ++ni)
            bfr[ni] = *(const bfrag*)(Bs + (wn * 96 + ni * 16 + l16) * 40 + quad * 8);
#pragma unroll
        for (int mi = 0; mi < 4; ++mi)
#pragma unroll
            for (int ni = 0; ni < 6; ++ni)
                acc[mi][ni] = __builtin_amdgcn_mfma_f32_16x16x32_bf16(af[mi], bfr[ni], acc[mi][ni], 0, 0, 0);
    }

    // epilogue: two 64-row halves through Cs, coalesced uint4 stores
    const int b   = m0 >> 11;
    const int tb0 = m0 & 2047;
    const size_t bh = (size_t)(b * 8 + h);
#pragma unroll
    for (int half = 0; half < 2; ++half) {
        __syncthreads();
        if (wm == half) {
#pragma unroll
            for (int mi = 0; mi < 4; ++mi)
#pragma unroll
                for (int ni = 0; ni < 6; ++ni)
#pragma unroll
                    for (int reg = 0; reg < 4; ++reg) {
                        int r = mi * 16 + quad * 4 + reg;          // 0..63 in half
                        int c = wn * 96 + ni * 16 + l16;           // 0..191
                        Cs[r * 200 + c] = f2bf_fast(acc[mi][ni][reg] + bvv[ni]);
                    }
        }
        __syncthreads();
        const int tb = tb0 + half * 64;
#pragma unroll
        for (int i = 0; i < 2; ++i) {
            int idx = tid + i * 256;            // 0..511
            int tl = idx >> 3, hc = (idx & 7) * 8;
            __align__(16) unsigned short tq[8], tk[8];
#pragma unroll
            for (int j = 0; j < 8; ++j) {
                tq[j] = Cs[tl * 200 + (hc + j) * 3 + 0];
                tk[j] = Cs[tl * 200 + (hc + j) * 3 + 1];
            }
            *(uint4*)(Qb + (bh * T_ + tb + tl) * HD_ + hc) = *(const uint4*)tq;
            *(uint4*)(Kb + (bh * T_ + tb + tl) * HD_ + hc) = *(const uint4*)tk;
        }
#pragma unroll
        for (int i = 0; i < 2; ++i) {
            int idx = tid + i * 256;
            int hd = idx >> 3, t8 = (idx & 7) * 8;
            __align__(16) unsigned short tv[8];
#pragma unroll
            for (int j = 0; j < 8; ++j)
                tv[j] = Cs[(t8 + j) * 200 + hd * 3 + 2];
            *(uint4*)(Vtb + (bh * HD_ + hd) * T_ + tb + t8) = *(const uint4*)tv;
        }
    }
}

// ---------------------------------------------------------------------------
// Kernel 3: flash attention, no-max softmax, per-tile mask flags.
// Unmasked tile: zero mask work. Masked tile: fp32 mask straight from global.
// ---------------------------------------------------------------------------
__global__ __launch_bounds__(256) void k_attn(const unsigned short* __restrict__ Q,
                                              const unsigned short* __restrict__ K,
                                              const unsigned short* __restrict__ Vt,
                                              const float* __restrict__ mask,
                                              const int* __restrict__ flags,
                                              float* __restrict__ out) {
    __shared__ __align__(16) unsigned short Ks[64 * 72];
    __shared__ __align__(16) unsigned short Vs[64 * 72];    // [dim][kv]
    __shared__ __align__(16) unsigned short Ps[4][16 * 72];

    const int tid = threadIdx.x;
    const int wave = tid >> 6, lane = tid & 63;
    const int quad = lane >> 4, l16 = lane & 15;
    const int bh = blockIdx.y, b = bh >> 3, h = bh & 7;
    const int qt = blockIdx.x;
    const int q0 = qt * 64;
    const int fbase = (b * 32 + qt) * 32;

    bfrag qf[2];
    {
        size_t qrow = ((size_t)bh * T_ + q0 + wave * 16 + l16) * HD_;
        qf[0] = *(const bfrag*)(Q + qrow + quad * 8);
        qf[1] = *(const bfrag*)(Q + qrow + 32 + quad * 8);
    }
    float lsum[4] = {0.f, 0.f, 0.f, 0.f};
    ffrag of[4];
#pragma unroll
    for (int nb = 0; nb < 4; ++nb) of[nb] = (ffrag){0.f, 0.f, 0.f, 0.f};

    for (int kt = 0; kt < 32; ++kt) {
        __syncthreads();
#pragma unroll
        for (int i = 0; i < 2; ++i) {
            int chunk = tid + i * 256;
            int r = chunk >> 3, c = chunk & 7;
            *(uint4*)(Ks + r * 72 + c * 8) =
                *(const uint4*)(K + ((size_t)bh * T_ + kt * 64 + r) * HD_ + c * 8);
            *(uint4*)(Vs + r * 72 + c * 8) =
                *(const uint4*)(Vt + ((size_t)bh * HD_ + r) * T_ + kt * 64 + c * 8);
        }
        const int fl = flags[fbase + kt];
        __syncthreads();
        // S = Q K^T  (4 n-subtiles of 16 kv cols)
        ffrag sf[4];
#pragma unroll
        for (int ns = 0; ns < 4; ++ns) {
            ffrag a = (ffrag){0.f, 0.f, 0.f, 0.f};
#pragma unroll
            for (int ks = 0; ks < 2; ++ks) {
                bfrag kf = *(const bfrag*)(Ks + (ns * 16 + l16) * 72 + (ks * 4 + quad) * 8);
                a = __builtin_amdgcn_mfma_f32_16x16x32_bf16(qf[ks], kf, a, 0, 0, 0);
            }
            sf[ns] = a;
        }
        // p = exp2(s*scale [+ (m-1)*1e4*log2e]); accumulate row-sum; P -> LDS
        if (fl) {
#pragma unroll
            for (int reg = 0; reg < 4; ++reg) {
                int rm = wave * 16 + quad * 4 + reg;
                const float* mrow = mask + ((size_t)b * T_ + q0 + rm) * T_ + kt * 64;
#pragma unroll
                for (int ns = 0; ns < 4; ++ns) {
                    float msk = mrow[ns * 16 + l16];
                    float p = __builtin_amdgcn_exp2f(
                        fmaf(sf[ns][reg], SCALE_L2E, (msk - 1.f) * MASK_L2E));
                    lsum[reg] += p;
                    Ps[wave][rm % 16 * 72 + ns * 16 + l16] = f2bf_fast(p);
                }
            }
        } else {
#pragma unroll
            for (int reg = 0; reg < 4; ++reg) {
#pragma unroll
                for (int ns = 0; ns < 4; ++ns) {
                    float p = __builtin_amdgcn_exp2f(sf[ns][reg] * SCALE_L2E);
                    lsum[reg] += p;
                    Ps[wave][(quad * 4 + reg) * 72 + ns * 16 + l16] = f2bf_fast(p);
                }
            }
        }
        // O += P V   (same-wave LDS round-trip, no barrier)
#pragma unroll
        for (int ks = 0; ks < 2; ++ks) {
            bfrag pf = *(const bfrag*)(&Ps[wave][l16 * 72 + (ks * 4 + quad) * 8]);
#pragma unroll
            for (int nb = 0; nb < 4; ++nb) {
                bfrag vf = *(const bfrag*)(Vs + (nb * 16 + l16) * 72 + (ks * 4 + quad) * 8);
                of[nb] = __builtin_amdgcn_mfma_f32_16x16x32_bf16(pf, vf, of[nb], 0, 0, 0);
            }
        }
    }
    // epilogue: shuffle-reduce row-sums, normalize, fp32 store
#pragma unroll
    for (int reg = 0; reg < 4; ++reg) {
        float s = lsum[reg];
#pragma unroll
        for (int d = 1; d < 16; d <<= 1) s += __shfl_xor(s, d, 64);
        float inv = 1.0f / s;
        int t = q0 + wave * 16 + quad * 4 + reg;
#pragma unroll
        for (int nb = 0; nb < 4; ++nb)
            out[((size_t)b * T_ + t) * DM_ + h * 64 + nb * 16 + l16] = of[nb][reg] * inv;
    }
}

// ---------------------------------------------------------------------------
extern "C" void kernel_launch(void* const* d_in, const int* in_sizes, int n_in,
                              void* d_out, int out_size, void* d_ws, size_t ws_size,
                              hipStream_t stream) {
    const float* X    = (const float*)d_in[0];   // [4,2048,512] fp32
    const float* mask = (const float*)d_in[1];   // [4,1,2048,2048] fp32
    const float* W    = (const float*)d_in[2];   // [512,1536] fp32
    const float* bias = (const float*)d_in[3];   // [1536] fp32
    float* outp = (float*)d_out;                 // [4,2048,512] fp32

    char* ws = (char*)d_ws;
    unsigned short* Wt  = (unsigned short*)(ws);              // 1.5 MB
    unsigned short* Qb  = (unsigned short*)(ws + 1572864);    // 8 MB
    unsigned short* Kb  = (unsigned short*)(ws + 9961472);    // 8 MB
    unsigned short* Vtb = (unsigned short*)(ws + 18350080);   // 8 MB
    int*            flg = (int*)(ws + 26738688);              // 16 KB (end ~26.75 MB)

    k_transposeW<<<dim3(24, 8),   256, 0, stream>>>(W, Wt);
    k_maskscan  <<<dim3(32, 128), 256, 0, stream>>>(mask, flg);
    k_gemm_qkv  <<<dim3(8, 64),   256, 0, stream>>>(X, Wt, bias, Qb, Kb, Vtb);
    k_attn      <<<dim3(32, 32),  256, 0, stream>>>(Qb, Kb, Vtb, mask, flg, outp);
}

// Round 7
// 241.685 us; speedup vs baseline: 1.0111x; 1.0111x over previous
//
#include <hip/hip_runtime.h>
#include <hip/hip_bf16.h>
#include <stdint.h>

#define B_   4
#define T_   2048
#define H_   8
#define HD_  64
#define DM_  512
#define N3_  1536

typedef short bf_el;
typedef __attribute__((ext_vector_type(8))) bf_el bfrag;   // 8 bf16 = 4 VGPRs
typedef __attribute__((ext_vector_type(4))) float ffrag;

#define SCALE_L2E  0.18033688011112043f   /* 0.125 * log2(e) */
#define MASK_L2E   14426.950408889634f    /* 1e4  * log2(e) */

static __device__ __forceinline__ unsigned short f2bf(float f) {      // RNE
    union { float f; unsigned int i; } v; v.f = f;
    unsigned int r = v.i + 0x7fff + ((v.i >> 16) & 1);
    return (unsigned short)(r >> 16);
}
static __device__ __forceinline__ unsigned short f2bf_fast(float f) { // round-half-up
    union { float f; unsigned int i; } v; v.f = f;
    return (unsigned short)((v.i + 0x8000u) >> 16);
}

// ---------------------------------------------------------------------------
// Kernel 0: W fp32 [512,1536] -> Wt bf16 [1536,512]
// ---------------------------------------------------------------------------
__global__ __launch_bounds__(256) void k_transposeW(const float* __restrict__ W,
                                                    unsigned short* __restrict__ Wt) {
    __shared__ __align__(16) unsigned short Ls[64 * 72];
    const int n0 = blockIdx.x * 64;
    const int k0 = blockIdx.y * 64;
    const int tid = threadIdx.x;
#pragma unroll
    for (int i = 0; i < 4; ++i) {
        int chunk = tid + i * 256;   // 0..1023
        int k = chunk >> 4;          // 0..63
        int c = chunk & 15;          // 0..15 (float4 chunks)
        float4 f = *(const float4*)(W + (size_t)(k0 + k) * N3_ + n0 + c * 4);
        unsigned short* p = Ls + k * 72 + c * 4;
        p[0] = f2bf(f.x); p[1] = f2bf(f.y); p[2] = f2bf(f.z); p[3] = f2bf(f.w);
    }
    __syncthreads();
    const int n = tid >> 2;
    const int g = tid & 3;
    __align__(16) unsigned short tmp[16];
#pragma unroll
    for (int i = 0; i < 16; ++i) tmp[i] = Ls[(g * 16 + i) * 72 + n];
    uint4* dst = (uint4*)(Wt + (size_t)(n0 + n) * DM_ + k0 + g * 16);
    dst[0] = *(const uint4*)(tmp);
    dst[1] = *(const uint4*)(tmp + 8);
}

// ---------------------------------------------------------------------------
// Kernel 1 (fused): role by blockIdx.y.
//  y <  64 : GEMM  X[8192,512] @ Wt^T + bias -> Q(pre-scaled)/K/Vt bf16,
//            128(m) x 192(n) tile = one head, register-prefetch pipeline.
//  y >= 64 : MASK SCAN (overlaps the GEMM): 512 blocks cover 4096 64x64
//            mask tiles; one wave per 2 tiles, ballot-only, no barriers.
// ---------------------------------------------------------------------------
__global__ __launch_bounds__(256) void k_gemm_qkv(const float* __restrict__ X,
                                                  const unsigned short* __restrict__ Wt,
                                                  const float* __restrict__ bias,
                                                  const float* __restrict__ mask,
                                                  int* __restrict__ flags,
                                                  unsigned short* __restrict__ Qb,
                                                  unsigned short* __restrict__ Kb,
                                                  unsigned short* __restrict__ Vtb) {
    // union: staging As[128*40](5120) + Bs[192*40](7680) == epilogue Cs[64*200](12800)
    __shared__ __align__(16) unsigned short SH[12800];

    const int tid  = threadIdx.x;
    const int wave = tid >> 6;
    const int lane = tid & 63;

    if (blockIdx.y >= 64) {
        // ---------------- mask-scan role ----------------
        const int e  = (blockIdx.y - 64) * 2 + (blockIdx.x >> 2);  // 0..127 = b*32+qt
        const int g  = blockIdx.x & 3;
        const int mb = e >> 5, qt = e & 31;
#pragma unroll
        for (int w2 = 0; w2 < 2; ++w2) {
            const int kt = g * 8 + wave * 2 + w2;
            bool any = false;
#pragma unroll
            for (int i = 0; i < 4; ++i) {
                const int row = i * 16 + (lane >> 2);
                const float* mp = mask + ((size_t)mb * T_ + qt * 64 + row) * T_
                                       + kt * 64 + (lane & 3) * 16;
#pragma unroll
                for (int j = 0; j < 4; ++j) {
                    float4 f = *(const float4*)(mp + j * 4);
                    any = any | (f.x != 1.f) | (f.y != 1.f) | (f.z != 1.f) | (f.w != 1.f);
                }
            }
            unsigned long long bal = __ballot(any);
            if (lane == 0) flags[e * 32 + kt] = (bal != 0ULL) ? 1 : 0;
        }
        return;
    }

    // ---------------- GEMM role ----------------
    unsigned short* As = SH;            // row stride 40 shorts (32 data + 8 pad)
    unsigned short* Bs = SH + 5120;
    unsigned short* Cs = SH;            // row stride 200 shorts (192 data + 8 pad)

    const int quad = lane >> 4;
    const int l16  = lane & 15;
    const int wm = wave >> 1, wn = wave & 1;    // 2x2 waves: 64 rows x 96 cols each
    const int m0 = blockIdx.y * 128;
    const int h  = blockIdx.x;                  // head
    const int n0 = h * 192;

    float bvv[6];
#pragma unroll
    for (int ni = 0; ni < 6; ++ni) bvv[ni] = bias[n0 + wn * 96 + ni * 16 + l16];

    ffrag acc[4][6];
#pragma unroll
    for (int i = 0; i < 4; ++i)
#pragma unroll
        for (int j = 0; j < 6; ++j) acc[i][j] = (ffrag){0.f, 0.f, 0.f, 0.f};

    const int ar0 = tid >> 2,            ac0 = tid & 3;
    const int ar1 = (tid + 256) >> 2,    ac1 = tid & 3;
    float4 pa[4];
    uint4  pb[3];
    const int br[3] = { tid >> 2, (tid + 256) >> 2, (tid + 512) >> 2 };
    const int bc    = tid & 3;

    {
        const float* xp0 = X + (size_t)(m0 + ar0) * DM_ + ac0 * 8;
        const float* xp1 = X + (size_t)(m0 + ar1) * DM_ + ac1 * 8;
        pa[0] = *(const float4*)xp0; pa[1] = *(const float4*)(xp0 + 4);
        pa[2] = *(const float4*)xp1; pa[3] = *(const float4*)(xp1 + 4);
#pragma unroll
        for (int i = 0; i < 3; ++i)
            pb[i] = *(const uint4*)(Wt + (size_t)(n0 + br[i]) * DM_ + bc * 8);
    }

    for (int kt = 0; kt < 16; ++kt) {
        __syncthreads();
        {
            __align__(16) unsigned short t8[8];
            t8[0] = f2bf_fast(pa[0].x); t8[1] = f2bf_fast(pa[0].y);
            t8[2] = f2bf_fast(pa[0].z); t8[3] = f2bf_fast(pa[0].w);
            t8[4] = f2bf_fast(pa[1].x); t8[5] = f2bf_fast(pa[1].y);
            t8[6] = f2bf_fast(pa[1].z); t8[7] = f2bf_fast(pa[1].w);
            *(uint4*)(As + ar0 * 40 + ac0 * 8) = *(const uint4*)t8;
            t8[0] = f2bf_fast(pa[2].x); t8[1] = f2bf_fast(pa[2].y);
            t8[2] = f2bf_fast(pa[2].z); t8[3] = f2bf_fast(pa[2].w);
            t8[4] = f2bf_fast(pa[3].x); t8[5] = f2bf_fast(pa[3].y);
            t8[6] = f2bf_fast(pa[3].z); t8[7] = f2bf_fast(pa[3].w);
            *(uint4*)(As + ar1 * 40 + ac1 * 8) = *(const uint4*)t8;
#pragma unroll
            for (int i = 0; i < 3; ++i)
                *(uint4*)(Bs + br[i] * 40 + bc * 8) = pb[i];
        }
        __syncthreads();
        if (kt < 15) {
            const float* xp0 = X + (size_t)(m0 + ar0) * DM_ + (kt + 1) * 32 + ac0 * 8;
            const float* xp1 = X + (size_t)(m0 + ar1) * DM_ + (kt + 1) * 32 + ac1 * 8;
            pa[0] = *(const float4*)xp0; pa[1] = *(const float4*)(xp0 + 4);
            pa[2] = *(const float4*)xp1; pa[3] = *(const float4*)(xp1 + 4);
#pragma unroll
            for (int i = 0; i < 3; ++i)
                pb[i] = *(const uint4*)(Wt + (size_t)(n0 + br[i]) * DM_ + (kt + 1) * 32 + bc * 8);
        }
        bfrag af[4], bfr[6];
#pragma unroll
        for (int mi = 0; mi < 4; ++mi)
            af[mi] = *(const bfrag*)(As + (wm * 64 + mi * 16 + l16) * 40 + quad * 8);
#pragma unroll
        for (int ni = 0; ni < 6; ++ni)
            bfr[ni] = *(const bfrag*)(Bs + (wn * 96 + ni * 16 + l16) * 40 + quad * 8);
#pragma unroll
        for (int mi = 0; mi < 4; ++mi)
#pragma unroll
            for (int ni = 0; ni < 6; ++ni)
                acc[mi][ni] = __builtin_amdgcn_mfma_f32_16x16x32_bf16(af[mi], bfr[ni], acc[mi][ni], 0, 0, 0);
    }

    // epilogue: two 64-row halves through Cs, coalesced uint4 stores.
    // Q columns (c%3==0) pre-scaled by 0.125*log2(e) so attn softmax is bare exp2.
    const int b   = m0 >> 11;
    const int tb0 = m0 & 2047;
    const size_t bh = (size_t)(b * 8 + h);
    float cscale[6];
#pragma unroll
    for (int ni = 0; ni < 6; ++ni) {
        int c = wn * 96 + ni * 16 + l16;
        cscale[ni] = (c % 3 == 0) ? SCALE_L2E : 1.0f;
    }
#pragma unroll
    for (int half = 0; half < 2; ++half) {
        __syncthreads();
        if (wm == half) {
#pragma unroll
            for (int mi = 0; mi < 4; ++mi)
#pragma unroll
                for (int ni = 0; ni < 6; ++ni)
#pragma unroll
                    for (int reg = 0; reg < 4; ++reg) {
                        int r = mi * 16 + quad * 4 + reg;          // 0..63 in half
                        int c = wn * 96 + ni * 16 + l16;           // 0..191
                        Cs[r * 200 + c] = f2bf_fast((acc[mi][ni][reg] + bvv[ni]) * cscale[ni]);
                    }
        }
        __syncthreads();
        const int tb = tb0 + half * 64;
#pragma unroll
        for (int i = 0; i < 2; ++i) {
            int idx = tid + i * 256;            // 0..511
            int tl = idx >> 3, hc = (idx & 7) * 8;
            __align__(16) unsigned short tq[8], tk[8];
#pragma unroll
            for (int j = 0; j < 8; ++j) {
                tq[j] = Cs[tl * 200 + (hc + j) * 3 + 0];
                tk[j] = Cs[tl * 200 + (hc + j) * 3 + 1];
            }
            *(uint4*)(Qb + (bh * T_ + tb + tl) * HD_ + hc) = *(const uint4*)tq;
            *(uint4*)(Kb + (bh * T_ + tb + tl) * HD_ + hc) = *(const uint4*)tk;
        }
#pragma unroll
        for (int i = 0; i < 2; ++i) {
            int idx = tid + i * 256;
            int hd = idx >> 3, t8 = (idx & 7) * 8;
            __align__(16) unsigned short tv[8];
#pragma unroll
            for (int j = 0; j < 8; ++j)
                tv[j] = Cs[(t8 + j) * 200 + hd * 3 + 2];
            *(uint4*)(Vtb + (bh * HD_ + hd) * T_ + tb + t8) = *(const uint4*)tv;
        }
    }
}

// ---------------------------------------------------------------------------
// Kernel 2: flash attention, no-max softmax (Q pre-scaled: p = exp2(s)),
// per-tile mask flags. Masked tile: fp32 mask straight from global.
// ---------------------------------------------------------------------------
__global__ __launch_bounds__(256) void k_attn(const unsigned short* __restrict__ Q,
                                              const unsigned short* __restrict__ K,
                                              const unsigned short* __restrict__ Vt,
                                              const float* __restrict__ mask,
                                              const int* __restrict__ flags,
                                              float* __restrict__ out) {
    __shared__ __align__(16) unsigned short Ks[64 * 72];
    __shared__ __align__(16) unsigned short Vs[64 * 72];    // [dim][kv]
    __shared__ __align__(16) unsigned short Ps[4][16 * 72];

    const int tid = threadIdx.x;
    const int wave = tid >> 6, lane = tid & 63;
    const int quad = lane >> 4, l16 = lane & 15;
    const int bh = blockIdx.y, b = bh >> 3, h = bh & 7;
    const int qt = blockIdx.x;
    const int q0 = qt * 64;
    const int fbase = (b * 32 + qt) * 32;

    bfrag qf[2];
    {
        size_t qrow = ((size_t)bh * T_ + q0 + wave * 16 + l16) * HD_;
        qf[0] = *(const bfrag*)(Q + qrow + quad * 8);
        qf[1] = *(const bfrag*)(Q + qrow + 32 + quad * 8);
    }
    float lsum[4] = {0.f, 0.f, 0.f, 0.f};
    ffrag of[4];
#pragma unroll
    for (int nb = 0; nb < 4; ++nb) of[nb] = (ffrag){0.f, 0.f, 0.f, 0.f};

    for (int kt = 0; kt < 32; ++kt) {
        __syncthreads();
#pragma unroll
        for (int i = 0; i < 2; ++i) {
            int chunk = tid + i * 256;
            int r = chunk >> 3, c = chunk & 7;
            *(uint4*)(Ks + r * 72 + c * 8) =
                *(const uint4*)(K + ((size_t)bh * T_ + kt * 64 + r) * HD_ + c * 8);
            *(uint4*)(Vs + r * 72 + c * 8) =
                *(const uint4*)(Vt + ((size_t)bh * HD_ + r) * T_ + kt * 64 + c * 8);
        }
        const int fl = flags[fbase + kt];
        __syncthreads();
        // S = Q K^T  (4 n-subtiles of 16 kv cols); S already includes softmax scale
        ffrag sf[4];
#pragma unroll
        for (int ns = 0; ns < 4; ++ns) {
            ffrag a = (ffrag){0.f, 0.f, 0.f, 0.f};
#pragma unroll
            for (int ks = 0; ks < 2; ++ks) {
                bfrag kf = *(const bfrag*)(Ks + (ns * 16 + l16) * 72 + (ks * 4 + quad) * 8);
                a = __builtin_amdgcn_mfma_f32_16x16x32_bf16(qf[ks], kf, a, 0, 0, 0);
            }
            sf[ns] = a;
        }
        // p = exp2(s [+ (m-1)*1e4*log2e]); accumulate row-sum; P -> LDS
        if (fl) {
#pragma unroll
            for (int reg = 0; reg < 4; ++reg) {
                int rm = wave * 16 + quad * 4 + reg;
                const float* mrow = mask + ((size_t)b * T_ + q0 + rm) * T_ + kt * 64;
#pragma unroll
                for (int ns = 0; ns < 4; ++ns) {
                    float msk = mrow[ns * 16 + l16];
                    float p = __builtin_amdgcn_exp2f(
                        fmaf(msk, MASK_L2E, sf[ns][reg] - MASK_L2E));
                    lsum[reg] += p;
                    Ps[wave][(quad * 4 + reg) * 72 + ns * 16 + l16] = f2bf_fast(p);
                }
            }
        } else {
#pragma unroll
            for (int reg = 0; reg < 4; ++reg) {
#pragma unroll
                for (int ns = 0; ns < 4; ++ns) {
                    float p = __builtin_amdgcn_exp2f(sf[ns][reg]);
                    lsum[reg] += p;
                    Ps[wave][(quad * 4 + reg) * 72 + ns * 16 + l16] = f2bf_fast(p);
                }
            }
        }
        // O += P V   (same-wave LDS round-trip, no barrier)
#pragma unroll
        for (int ks = 0; ks < 2; ++ks) {
            bfrag pf = *(const bfrag*)(&Ps[wave][l16 * 72 + (ks * 4 + quad) * 8]);
#pragma unroll
            for (int nb = 0; nb < 4; ++nb) {
                bfrag vf = *(const bfrag*)(Vs + (nb * 16 + l16) * 72 + (ks * 4 + quad) * 8);
                of[nb] = __builtin_amdgcn_mfma_f32_16x16x32_bf16(pf, vf, of[nb], 0, 0, 0);
            }
        }
    }
    // epilogue: shuffle-reduce row-sums, normalize, fp32 store
#pragma unroll
    for (int reg = 0; reg < 4; ++reg) {
        float s = lsum[reg];
#pragma unroll
        for (int d = 1; d < 16; d <<= 1) s += __shfl_xor(s, d, 64);
        float inv = 1.0f / s;
        int t = q0 + wave * 16 + quad * 4 + reg;
#pragma unroll
        for (int nb = 0; nb < 4; ++nb)
            out[((size_t)b * T_ + t) * DM_ + h * 64 + nb * 16 + l16] = of[nb][reg] * inv;
    }
}

// ---------------------------------------------------------------------------
extern "C" void kernel_launch(void* const* d_in, const int* in_sizes, int n_in,
                              void* d_out, int out_size, void* d_ws, size_t ws_size,
                              hipStream_t stream) {
    const float* X    = (const float*)d_in[0];   // [4,2048,512] fp32
    const float* mask = (const float*)d_in[1];   // [4,1,2048,2048] fp32
    const float* W    = (const float*)d_in[2];   // [512,1536] fp32
    const float* bias = (const float*)d_in[3];   // [1536] fp32
    float* outp = (float*)d_out;                 // [4,2048,512] fp32

    char* ws = (char*)d_ws;
    unsigned short* Wt  = (unsigned short*)(ws);              // 1.5 MB
    unsigned short* Qb  = (unsigned short*)(ws + 1572864);    // 8 MB
    unsigned short* Kb  = (unsigned short*)(ws + 9961472);    // 8 MB
    unsigned short* Vtb = (unsigned short*)(ws + 18350080);   // 8 MB
    int*            flg = (int*)(ws + 26738688);              // 16 KB (end ~26.75 MB)

    k_transposeW<<<dim3(24, 8),  256, 0, stream>>>(W, Wt);
    k_gemm_qkv  <<<dim3(8, 128), 256, 0, stream>>>(X, Wt, bias, mask, flg, Qb, Kb, Vtb);
    k_attn      <<<dim3(32, 32), 256, 0, stream>>>(Qb, Kb, Vtb, mask, flg, outp);
}

// Round 8
// 219.595 us; speedup vs baseline: 1.1128x; 1.1006x over previous
//
#include <hip/hip_runtime.h>
#include <hip/hip_bf16.h>
#include <stdint.h>

#define B_   4
#define T_   2048
#define H_   8
#define HD_  64
#define DM_  512
#define N3_  1536

typedef short bf_el;
typedef __attribute__((ext_vector_type(8))) bf_el bfrag;   // 8 bf16 = 4 VGPRs
typedef __attribute__((ext_vector_type(4))) float ffrag;

#define SCALE_L2E  0.18033688011112043f   /* 0.125 * log2(e) */
#define MASK_L2E   14426.950408889634f    /* 1e4  * log2(e) */

static __device__ __forceinline__ unsigned short f2bf(float f) {      // RNE
    union { float f; unsigned int i; } v; v.f = f;
    unsigned int r = v.i + 0x7fff + ((v.i >> 16) & 1);
    return (unsigned short)(r >> 16);
}
static __device__ __forceinline__ unsigned short f2bf_fast(float f) { // round-half-up
    union { float f; unsigned int i; } v; v.f = f;
    return (unsigned short)((v.i + 0x8000u) >> 16);
}

// ---------------------------------------------------------------------------
// Kernel 0 (prep, 3 BW-bound roles by blockIdx.x):
//  [0,512)  : mask scan -> per-64x64-tile flag (row-coalesced, int compares)
//  [512,768): X fp32 -> bf16 (removes f2bf from the GEMM hot loop)
//  [768,960): W [512,1536] fp32 -> Wt bf16 [1536,512]
// ---------------------------------------------------------------------------
__global__ __launch_bounds__(256) void k_prep(const float* __restrict__ W,
                                              const float* __restrict__ X,
                                              const float* __restrict__ mask,
                                              unsigned short* __restrict__ Wt,
                                              unsigned short* __restrict__ Xb,
                                              int* __restrict__ flags) {
    __shared__ __align__(16) unsigned short Ls[64 * 72];
    const int bid = blockIdx.x;
    const int tid = threadIdx.x;

    if (bid < 512) {
        // ---- mask scan: 8 tiles/block (4 waves x 2) ----
        const int wave = tid >> 6, lane = tid & 63;
        const int e  = bid >> 2;          // 0..127 = b*32 + qt64
        const int g  = bid & 3;
        const int mb = e >> 5, qt = e & 31;
#pragma unroll
        for (int w2 = 0; w2 < 2; ++w2) {
            const int kt = g * 8 + wave * 2 + w2;
            unsigned int acc = 0u;
#pragma unroll
            for (int j = 0; j < 16; ++j) {
                const int row = j * 4 + (lane >> 4);
                const uint4 u = *(const uint4*)(mask + ((size_t)mb * T_ + qt * 64 + row) * T_
                                                     + kt * 64 + (lane & 15) * 4);
                acc |= (u.x ^ 0x3F800000u) | (u.y ^ 0x3F800000u) |
                       (u.z ^ 0x3F800000u) | (u.w ^ 0x3F800000u);
            }
            unsigned long long bal = __ballot(acc != 0u);
            if (lane == 0) flags[e * 32 + kt] = (bal != 0ULL) ? 1 : 0;
        }
        return;
    }
    if (bid < 768) {
        // ---- X convert: 16384 floats per block ----
        const int b2 = bid - 512;
        const float* src = X + (size_t)b2 * 16384;
        unsigned short* dst = Xb + (size_t)b2 * 16384;
#pragma unroll
        for (int j = 0; j < 8; ++j) {
            int idx = j * 512 + tid * 2;           // float4-pair index
            float4 f0 = *(const float4*)(src + idx * 4);
            float4 f1 = *(const float4*)(src + idx * 4 + 4);
            __align__(16) unsigned short t8[8];
            t8[0] = f2bf_fast(f0.x); t8[1] = f2bf_fast(f0.y);
            t8[2] = f2bf_fast(f0.z); t8[3] = f2bf_fast(f0.w);
            t8[4] = f2bf_fast(f1.x); t8[5] = f2bf_fast(f1.y);
            t8[6] = f2bf_fast(f1.z); t8[7] = f2bf_fast(f1.w);
            *(uint4*)(dst + idx * 4) = *(const uint4*)t8;
        }
        return;
    }
    // ---- W transpose+convert ----
    {
        const int t  = bid - 768;                 // 0..191 = 24 x 8
        const int n0 = (t % 24) * 64;
        const int k0 = (t / 24) * 64;
#pragma unroll
        for (int i = 0; i < 4; ++i) {
            int chunk = tid + i * 256;            // 0..1023
            int k = chunk >> 4;
            int c = chunk & 15;
            float4 f = *(const float4*)(W + (size_t)(k0 + k) * N3_ + n0 + c * 4);
            unsigned short* p = Ls + k * 72 + c * 4;
            p[0] = f2bf(f.x); p[1] = f2bf(f.y); p[2] = f2bf(f.z); p[3] = f2bf(f.w);
        }
        __syncthreads();
        const int n = tid >> 2;
        const int g = tid & 3;
        __align__(16) unsigned short tmp[16];
#pragma unroll
        for (int i = 0; i < 16; ++i) tmp[i] = Ls[(g * 16 + i) * 72 + n];
        uint4* dst = (uint4*)(Wt + (size_t)(n0 + n) * DM_ + k0 + g * 16);
        dst[0] = *(const uint4*)(tmp);
        dst[1] = *(const uint4*)(tmp + 8);
    }
}

// ---------------------------------------------------------------------------
// Kernel 1: Xb bf16 [8192,512] @ Wt^T + bias -> Q(pre-scaled)/K/Vt bf16.
// 128(m) x 192(n) tile = one head per block; plain sync uint4 staging
// (no conversion, no prefetch regs -> occupancy back up).
// ---------------------------------------------------------------------------
__global__ __launch_bounds__(256) void k_gemm_qkv(const unsigned short* __restrict__ Xb,
                                                  const unsigned short* __restrict__ Wt,
                                                  const float* __restrict__ bias,
                                                  unsigned short* __restrict__ Qb,
                                                  unsigned short* __restrict__ Kb,
                                                  unsigned short* __restrict__ Vtb) {
    // union: staging As[128*40](5120) + Bs[192*40](7680) == epilogue Cs[64*200](12800)
    __shared__ __align__(16) unsigned short SH[12800];
    unsigned short* As = SH;            // row stride 40 shorts (32 data + 8 pad)
    unsigned short* Bs = SH + 5120;
    unsigned short* Cs = SH;            // row stride 200 shorts (192 data + 8 pad)

    const int tid  = threadIdx.x;
    const int wave = tid >> 6;
    const int lane = tid & 63;
    const int quad = lane >> 4;
    const int l16  = lane & 15;
    const int wm = wave >> 1, wn = wave & 1;    // 2x2 waves: 64 rows x 96 cols each
    const int m0 = blockIdx.y * 128;
    const int h  = blockIdx.x;                  // head
    const int n0 = h * 192;

    float bvv[6];
#pragma unroll
    for (int ni = 0; ni < 6; ++ni) bvv[ni] = bias[n0 + wn * 96 + ni * 16 + l16];

    ffrag acc[4][6];
#pragma unroll
    for (int i = 0; i < 4; ++i)
#pragma unroll
        for (int j = 0; j < 6; ++j) acc[i][j] = (ffrag){0.f, 0.f, 0.f, 0.f};

    for (int kt = 0; kt < 16; ++kt) {
        __syncthreads();
        // A: 128 rows x 32 bf16 (512 chunks), B: 192 rows x 32 (768 chunks)
#pragma unroll
        for (int i = 0; i < 2; ++i) {
            int chunk = tid + i * 256;
            int r = chunk >> 2, c = chunk & 3;
            *(uint4*)(As + r * 40 + c * 8) =
                *(const uint4*)(Xb + (size_t)(m0 + r) * DM_ + kt * 32 + c * 8);
        }
#pragma unroll
        for (int i = 0; i < 3; ++i) {
            int chunk = tid + i * 256;
            int r = chunk >> 2, c = chunk & 3;
            *(uint4*)(Bs + r * 40 + c * 8) =
                *(const uint4*)(Wt + (size_t)(n0 + r) * DM_ + kt * 32 + c * 8);
        }
        __syncthreads();
        bfrag af[4], bfr[6];
#pragma unroll
        for (int mi = 0; mi < 4; ++mi)
            af[mi] = *(const bfrag*)(As + (wm * 64 + mi * 16 + l16) * 40 + quad * 8);
#pragma unroll
        for (int ni = 0; ni < 6; ++ni)
            bfr[ni] = *(const bfrag*)(Bs + (wn * 96 + ni * 16 + l16) * 40 + quad * 8);
#pragma unroll
        for (int mi = 0; mi < 4; ++mi)
#pragma unroll
            for (int ni = 0; ni < 6; ++ni)
                acc[mi][ni] = __builtin_amdgcn_mfma_f32_16x16x32_bf16(af[mi], bfr[ni], acc[mi][ni], 0, 0, 0);
    }

    // epilogue: two 64-row halves through Cs, coalesced uint4 stores.
    // Q columns (c%3==0) pre-scaled by 0.125*log2(e) so attn softmax is bare exp2.
    const int b   = m0 >> 11;
    const int tb0 = m0 & 2047;
    const size_t bh = (size_t)(b * 8 + h);
    float cscale[6];
#pragma unroll
    for (int ni = 0; ni < 6; ++ni) {
        int c = wn * 96 + ni * 16 + l16;
        cscale[ni] = (c % 3 == 0) ? SCALE_L2E : 1.0f;
    }
#pragma unroll
    for (int half = 0; half < 2; ++half) {
        __syncthreads();
        if (wm == half) {
#pragma unroll
            for (int mi = 0; mi < 4; ++mi)
#pragma unroll
                for (int ni = 0; ni < 6; ++ni)
#pragma unroll
                    for (int reg = 0; reg < 4; ++reg) {
                        int r = mi * 16 + quad * 4 + reg;          // 0..63 in half
                        int c = wn * 96 + ni * 16 + l16;           // 0..191
                        Cs[r * 200 + c] = f2bf_fast((acc[mi][ni][reg] + bvv[ni]) * cscale[ni]);
                    }
        }
        __syncthreads();
        const int tb = tb0 + half * 64;
#pragma unroll
        for (int i = 0; i < 2; ++i) {
            int idx = tid + i * 256;            // 0..511
            int tl = idx >> 3, hc = (idx & 7) * 8;
            __align__(16) unsigned short tq[8], tk[8];
#pragma unroll
            for (int j = 0; j < 8; ++j) {
                tq[j] = Cs[tl * 200 + (hc + j) * 3 + 0];
                tk[j] = Cs[tl * 200 + (hc + j) * 3 + 1];
            }
            *(uint4*)(Qb + (bh * T_ + tb + tl) * HD_ + hc) = *(const uint4*)tq;
            *(uint4*)(Kb + (bh * T_ + tb + tl) * HD_ + hc) = *(const uint4*)tk;
        }
#pragma unroll
        for (int i = 0; i < 2; ++i) {
            int idx = tid + i * 256;
            int hd = idx >> 3, t8 = (idx & 7) * 8;
            __align__(16) unsigned short tv[8];
#pragma unroll
            for (int j = 0; j < 8; ++j)
                tv[j] = Cs[(t8 + j) * 200 + hd * 3 + 2];
            *(uint4*)(Vtb + (bh * HD_ + hd) * T_ + tb + t8) = *(const uint4*)tv;
        }
    }
}

// ---------------------------------------------------------------------------
// Kernel 2: flash attention, 128-q-row tile (2 row-groups per wave),
// no-max softmax (Q pre-scaled: p = exp2(s)), per-64x64-tile mask flags.
// ---------------------------------------------------------------------------
__global__ __launch_bounds__(256) void k_attn(const unsigned short* __restrict__ Q,
                                              const unsigned short* __restrict__ K,
                                              const unsigned short* __restrict__ Vt,
                                              const float* __restrict__ mask,
                                              const int* __restrict__ flags,
                                              float* __restrict__ out) {
    __shared__ __align__(16) unsigned short Ks[64 * 72];
    __shared__ __align__(16) unsigned short Vs[64 * 72];    // [dim][kv]
    __shared__ __align__(16) unsigned short Ps[4][16 * 72];

    const int tid = threadIdx.x;
    const int wave = tid >> 6, lane = tid & 63;
    const int quad = lane >> 4, l16 = lane & 15;
    const int bh = blockIdx.y, b = bh >> 3, h = bh & 7;
    const int qt = blockIdx.x;           // 0..15
    const int q0 = qt * 128;

    bfrag qf[2][2];
#pragma unroll
    for (int g = 0; g < 2; ++g) {
        size_t qrow = ((size_t)bh * T_ + q0 + wave * 32 + g * 16 + l16) * HD_;
        qf[g][0] = *(const bfrag*)(Q + qrow + quad * 8);
        qf[g][1] = *(const bfrag*)(Q + qrow + 32 + quad * 8);
    }
    float lsum[2][4] = {{0.f,0.f,0.f,0.f},{0.f,0.f,0.f,0.f}};
    ffrag of[2][4];
#pragma unroll
    for (int g = 0; g < 2; ++g)
#pragma unroll
        for (int nb = 0; nb < 4; ++nb) of[g][nb] = (ffrag){0.f, 0.f, 0.f, 0.f};

    const int fbase0 = (b * 32 + qt * 2) * 32;
    const int fbase1 = (b * 32 + qt * 2 + 1) * 32;

    for (int kt = 0; kt < 32; ++kt) {
        __syncthreads();
#pragma unroll
        for (int i = 0; i < 2; ++i) {
            int chunk = tid + i * 256;
            int r = chunk >> 3, c = chunk & 7;
            *(uint4*)(Ks + r * 72 + c * 8) =
                *(const uint4*)(K + ((size_t)bh * T_ + kt * 64 + r) * HD_ + c * 8);
            *(uint4*)(Vs + r * 72 + c * 8) =
                *(const uint4*)(Vt + ((size_t)bh * HD_ + r) * T_ + kt * 64 + c * 8);
        }
        int fl[2];
        fl[0] = flags[fbase0 + kt];
        fl[1] = flags[fbase1 + kt];
        __syncthreads();
        // V fragments once per kt (shared by both row-groups)
        bfrag vf[2][4];
#pragma unroll
        for (int ks = 0; ks < 2; ++ks)
#pragma unroll
            for (int nb = 0; nb < 4; ++nb)
                vf[ks][nb] = *(const bfrag*)(Vs + (nb * 16 + l16) * 72 + (ks * 4 + quad) * 8);

#pragma unroll
        for (int g = 0; g < 2; ++g) {
            // S = Q K^T (scale folded into Q)
            ffrag sf[4];
#pragma unroll
            for (int ns = 0; ns < 4; ++ns) {
                ffrag a = (ffrag){0.f, 0.f, 0.f, 0.f};
#pragma unroll
                for (int ks = 0; ks < 2; ++ks) {
                    bfrag kf = *(const bfrag*)(Ks + (ns * 16 + l16) * 72 + (ks * 4 + quad) * 8);
                    a = __builtin_amdgcn_mfma_f32_16x16x32_bf16(qf[g][ks], kf, a, 0, 0, 0);
                }
                sf[ns] = a;
            }
            // p = exp2(s [+ (m-1)*1e4*log2e]); row-sum; P -> LDS (same-wave)
            if (fl[g]) {
#pragma unroll
                for (int reg = 0; reg < 4; ++reg) {
                    int tq = q0 + wave * 32 + g * 16 + quad * 4 + reg;
                    const float* mrow = mask + ((size_t)b * T_ + tq) * T_ + kt * 64;
#pragma unroll
                    for (int ns = 0; ns < 4; ++ns) {
                        float msk = mrow[ns * 16 + l16];
                        float p = __builtin_amdgcn_exp2f(
                            fmaf(msk, MASK_L2E, sf[ns][reg] - MASK_L2E));
                        lsum[g][reg] += p;
                        Ps[wave][(quad * 4 + reg) * 72 + ns * 16 + l16] = f2bf_fast(p);
                    }
                }
            } else {
#pragma unroll
                for (int reg = 0; reg < 4; ++reg) {
#pragma unroll
                    for (int ns = 0; ns < 4; ++ns) {
                        float p = __builtin_amdgcn_exp2f(sf[ns][reg]);
                        lsum[g][reg] += p;
                        Ps[wave][(quad * 4 + reg) * 72 + ns * 16 + l16] = f2bf_fast(p);
                    }
                }
            }
            // O_g += P_g V
#pragma unroll
            for (int ks = 0; ks < 2; ++ks) {
                bfrag pf = *(const bfrag*)(&Ps[wave][l16 * 72 + (ks * 4 + quad) * 8]);
#pragma unroll
                for (int nb = 0; nb < 4; ++nb)
                    of[g][nb] = __builtin_amdgcn_mfma_f32_16x16x32_bf16(pf, vf[ks][nb], of[g][nb], 0, 0, 0);
            }
        }
    }
    // epilogue: shuffle-reduce row-sums, normalize, fp32 store
#pragma unroll
    for (int g = 0; g < 2; ++g)
#pragma unroll
    for (int reg = 0; reg < 4; ++reg) {
        float s = lsum[g][reg];
#pragma unroll
        for (int d = 1; d < 16; d <<= 1) s += __shfl_xor(s, d, 64);
        float inv = 1.0f / s;
        int t = q0 + wave * 32 + g * 16 + quad * 4 + reg;
#pragma unroll
        for (int nb = 0; nb < 4; ++nb)
            out[((size_t)b * T_ + t) * DM_ + h * 64 + nb * 16 + l16] = of[g][nb][reg] * inv;
    }
}

// ---------------------------------------------------------------------------
extern "C" void kernel_launch(void* const* d_in, const int* in_sizes, int n_in,
                              void* d_out, int out_size, void* d_ws, size_t ws_size,
                              hipStream_t stream) {
    const float* X    = (const float*)d_in[0];   // [4,2048,512] fp32
    const float* mask = (const float*)d_in[1];   // [4,1,2048,2048] fp32
    const float* W    = (const float*)d_in[2];   // [512,1536] fp32
    const float* bias = (const float*)d_in[3];   // [1536] fp32
    float* outp = (float*)d_out;                 // [4,2048,512] fp32

    char* ws = (char*)d_ws;
    unsigned short* Wt  = (unsigned short*)(ws);              // 1.5 MB
    unsigned short* Xb  = (unsigned short*)(ws + 1572864);    // 8 MB
    unsigned short* Qb  = (unsigned short*)(ws + 9961472);    // 8 MB
    unsigned short* Kb  = (unsigned short*)(ws + 18350080);   // 8 MB
    unsigned short* Vtb = (unsigned short*)(ws + 26738688);   // 8 MB
    int*            flg = (int*)(ws + 35127296);              // 16 KB (end ~35.1 MB)

    k_prep     <<<dim3(960),    256, 0, stream>>>(W, X, mask, Wt, Xb, flg);
    k_gemm_qkv <<<dim3(8, 64),  256, 0, stream>>>(Xb, Wt, bias, Qb, Kb, Vtb);
    k_attn     <<<dim3(16, 32), 256, 0, stream>>>(Qb, Kb, Vtb, mask, flg, outp);
}

// Round 9
// 215.771 us; speedup vs baseline: 1.1325x; 1.0177x over previous
//
#include <hip/hip_runtime.h>
#include <hip/hip_bf16.h>
#include <stdint.h>

#define B_   4
#define T_   2048
#define H_   8
#define HD_  64
#define DM_  512
#define N3_  1536

typedef short bf_el;
typedef __attribute__((ext_vector_type(8))) bf_el bfrag;   // 8 bf16 = 4 VGPRs
typedef __attribute__((ext_vector_type(4))) float ffrag;

#define SCALE_L2E  0.18033688011112043f   /* 0.125 * log2(e) */
#define MASK_L2E   14426.950408889634f    /* 1e4  * log2(e) */

static __device__ __forceinline__ unsigned short f2bf(float f) {      // RNE
    union { float f; unsigned int i; } v; v.f = f;
    unsigned int r = v.i + 0x7fff + ((v.i >> 16) & 1);
    return (unsigned short)(r >> 16);
}
static __device__ __forceinline__ unsigned short f2bf_fast(float f) { // round-half-up
    union { float f; unsigned int i; } v; v.f = f;
    return (unsigned short)((v.i + 0x8000u) >> 16);
}

// ---------------------------------------------------------------------------
// Kernel 0 (prep, 3 BW-bound roles by blockIdx.x):
//  [0,512)  : mask scan, CONTIGUOUS 128KB/block; atomicOr only on mismatch
//  [512,768): X fp32 -> bf16
//  [768,960): W [512,1536] fp32 -> Wt bf16 [1536,512]
// flags must be pre-zeroed (hipMemsetAsync in kernel_launch).
// ---------------------------------------------------------------------------
__global__ __launch_bounds__(256) void k_prep(const float* __restrict__ W,
                                              const float* __restrict__ X,
                                              const float* __restrict__ mask,
                                              unsigned short* __restrict__ Wt,
                                              unsigned short* __restrict__ Xb,
                                              int* __restrict__ flags) {
    __shared__ __align__(16) unsigned short Ls[64 * 72];
    const int bid = blockIdx.x;
    const int tid = threadIdx.x;

    if (bid < 512) {
        // ---- mask scan: 16 consecutive mask rows per block (128 KB) ----
        const int R0 = bid * 16;              // global row in [0, 8192)
        const int mb = R0 >> 11;              // batch
        const int q0 = R0 & 2047;
        const int e  = mb * 32 + (q0 >> 6);   // flag row  (b*32 + qt64)
        const int wave = tid >> 6, lane = tid & 63;
        unsigned int acc = 0u;
        const float* base = mask + (size_t)R0 * T_ + tid * 8;
#pragma unroll
        for (int rr = 0; rr < 16; ++rr) {
            const uint4 u0 = *(const uint4*)(base + (size_t)rr * T_);
            const uint4 u1 = *(const uint4*)(base + (size_t)rr * T_ + 4);
            acc |= (u0.x ^ 0x3F800000u) | (u0.y ^ 0x3F800000u) |
                   (u0.z ^ 0x3F800000u) | (u0.w ^ 0x3F800000u) |
                   (u1.x ^ 0x3F800000u) | (u1.y ^ 0x3F800000u) |
                   (u1.z ^ 0x3F800000u) | (u1.w ^ 0x3F800000u);
        }
        unsigned long long bal = __ballot(acc != 0u);   // lane 8j..8j+7 = kt 8w+j
        if (lane == 0 && bal != 0ULL) {
#pragma unroll
            for (int j = 0; j < 8; ++j)
                if ((bal >> (8 * j)) & 0xFFULL)
                    atomicOr(&flags[e * 32 + wave * 8 + j], 1);
        }
        return;
    }
    if (bid < 768) {
        // ---- X convert: 16384 floats per block ----
        const int b2 = bid - 512;
        const float* src = X + (size_t)b2 * 16384;
        unsigned short* dst = Xb + (size_t)b2 * 16384;
#pragma unroll
        for (int j = 0; j < 8; ++j) {
            int idx = j * 512 + tid * 2;
            float4 f0 = *(const float4*)(src + idx * 4);
            float4 f1 = *(const float4*)(src + idx * 4 + 4);
            __align__(16) unsigned short t8[8];
            t8[0] = f2bf_fast(f0.x); t8[1] = f2bf_fast(f0.y);
            t8[2] = f2bf_fast(f0.z); t8[3] = f2bf_fast(f0.w);
            t8[4] = f2bf_fast(f1.x); t8[5] = f2bf_fast(f1.y);
            t8[6] = f2bf_fast(f1.z); t8[7] = f2bf_fast(f1.w);
            *(uint4*)(dst + idx * 4) = *(const uint4*)t8;
        }
        return;
    }
    // ---- W transpose+convert ----
    {
        const int t  = bid - 768;                 // 0..191 = 24 x 8
        const int n0 = (t % 24) * 64;
        const int k0 = (t / 24) * 64;
#pragma unroll
        for (int i = 0; i < 4; ++i) {
            int chunk = tid + i * 256;
            int k = chunk >> 4;
            int c = chunk & 15;
            float4 f = *(const float4*)(W + (size_t)(k0 + k) * N3_ + n0 + c * 4);
            unsigned short* p = Ls + k * 72 + c * 4;
            p[0] = f2bf(f.x); p[1] = f2bf(f.y); p[2] = f2bf(f.z); p[3] = f2bf(f.w);
        }
        __syncthreads();
        const int n = tid >> 2;
        const int g = tid & 3;
        __align__(16) unsigned short tmp[16];
#pragma unroll
        for (int i = 0; i < 16; ++i) tmp[i] = Ls[(g * 16 + i) * 72 + n];
        uint4* dst = (uint4*)(Wt + (size_t)(n0 + n) * DM_ + k0 + g * 16);
        dst[0] = *(const uint4*)(tmp);
        dst[1] = *(const uint4*)(tmp + 8);
    }
}

// ---------------------------------------------------------------------------
// Kernel 1: Xb bf16 [8192,512] @ Wt^T + bias -> Q(pre-scaled)/K/Vt bf16.
// 128(m) x 192(n) tile = one head. Flat grid bid = h*64 + mt so XCD = mt%8:
// the A-tile is L2-resident on one XCD and reused by all 8 head-blocks.
// ---------------------------------------------------------------------------
__global__ __launch_bounds__(256) void k_gemm_qkv(const unsigned short* __restrict__ Xb,
                                                  const unsigned short* __restrict__ Wt,
                                                  const float* __restrict__ bias,
                                                  unsigned short* __restrict__ Qb,
                                                  unsigned short* __restrict__ Kb,
                                                  unsigned short* __restrict__ Vtb) {
    // union: staging As[128*40](5120) + Bs[192*40](7680) == epilogue Cs[64*200](12800)
    __shared__ __align__(16) unsigned short SH[12800];
    unsigned short* As = SH;            // row stride 40 shorts (32 data + 8 pad)
    unsigned short* Bs = SH + 5120;
    unsigned short* Cs = SH;            // row stride 200 shorts (192 data + 8 pad)

    const int tid  = threadIdx.x;
    const int wave = tid >> 6;
    const int lane = tid & 63;
    const int quad = lane >> 4;
    const int l16  = lane & 15;
    const int wm = wave >> 1, wn = wave & 1;    // 2x2 waves: 64 rows x 96 cols each
    const int h  = blockIdx.x >> 6;             // head
    const int m0 = (blockIdx.x & 63) * 128;
    const int n0 = h * 192;

    float bvv[6];
#pragma unroll
    for (int ni = 0; ni < 6; ++ni) bvv[ni] = bias[n0 + wn * 96 + ni * 16 + l16];

    ffrag acc[4][6];
#pragma unroll
    for (int i = 0; i < 4; ++i)
#pragma unroll
        for (int j = 0; j < 6; ++j) acc[i][j] = (ffrag){0.f, 0.f, 0.f, 0.f};

    for (int kt = 0; kt < 16; ++kt) {
        __syncthreads();
#pragma unroll
        for (int i = 0; i < 2; ++i) {
            int chunk = tid + i * 256;
            int r = chunk >> 2, c = chunk & 3;
            *(uint4*)(As + r * 40 + c * 8) =
                *(const uint4*)(Xb + (size_t)(m0 + r) * DM_ + kt * 32 + c * 8);
        }
#pragma unroll
        for (int i = 0; i < 3; ++i) {
            int chunk = tid + i * 256;
            int r = chunk >> 2, c = chunk & 3;
            *(uint4*)(Bs + r * 40 + c * 8) =
                *(const uint4*)(Wt + (size_t)(n0 + r) * DM_ + kt * 32 + c * 8);
        }
        __syncthreads();
        bfrag af[4], bfr[6];
#pragma unroll
        for (int mi = 0; mi < 4; ++mi)
            af[mi] = *(const bfrag*)(As + (wm * 64 + mi * 16 + l16) * 40 + quad * 8);
#pragma unroll
        for (int ni = 0; ni < 6; ++ni)
            bfr[ni] = *(const bfrag*)(Bs + (wn * 96 + ni * 16 + l16) * 40 + quad * 8);
#pragma unroll
        for (int mi = 0; mi < 4; ++mi)
#pragma unroll
            for (int ni = 0; ni < 6; ++ni)
                acc[mi][ni] = __builtin_amdgcn_mfma_f32_16x16x32_bf16(af[mi], bfr[ni], acc[mi][ni], 0, 0, 0);
    }

    // epilogue: two 64-row halves through Cs, coalesced uint4 stores.
    // Q columns (c%3==0) pre-scaled by 0.125*log2(e) so attn softmax is bare exp2.
    const int b   = m0 >> 11;
    const int tb0 = m0 & 2047;
    const size_t bh = (size_t)(b * 8 + h);
    float cscale[6];
#pragma unroll
    for (int ni = 0; ni < 6; ++ni) {
        int c = wn * 96 + ni * 16 + l16;
        cscale[ni] = (c % 3 == 0) ? SCALE_L2E : 1.0f;
    }
#pragma unroll
    for (int half = 0; half < 2; ++half) {
        __syncthreads();
        if (wm == half) {
#pragma unroll
            for (int mi = 0; mi < 4; ++mi)
#pragma unroll
                for (int ni = 0; ni < 6; ++ni)
#pragma unroll
                    for (int reg = 0; reg < 4; ++reg) {
                        int r = mi * 16 + quad * 4 + reg;          // 0..63 in half
                        int c = wn * 96 + ni * 16 + l16;           // 0..191
                        Cs[r * 200 + c] = f2bf_fast((acc[mi][ni][reg] + bvv[ni]) * cscale[ni]);
                    }
        }
        __syncthreads();
        const int tb = tb0 + half * 64;
#pragma unroll
        for (int i = 0; i < 2; ++i) {
            int idx = tid + i * 256;            // 0..511
            int tl = idx >> 3, hc = (idx & 7) * 8;
            __align__(16) unsigned short tq[8], tk[8];
#pragma unroll
            for (int j = 0; j < 8; ++j) {
                tq[j] = Cs[tl * 200 + (hc + j) * 3 + 0];
                tk[j] = Cs[tl * 200 + (hc + j) * 3 + 1];
            }
            *(uint4*)(Qb + (bh * T_ + tb + tl) * HD_ + hc) = *(const uint4*)tq;
            *(uint4*)(Kb + (bh * T_ + tb + tl) * HD_ + hc) = *(const uint4*)tk;
        }
#pragma unroll
        for (int i = 0; i < 2; ++i) {
            int idx = tid + i * 256;
            int hd = idx >> 3, t8 = (idx & 7) * 8;
            __align__(16) unsigned short tv[8];
#pragma unroll
            for (int j = 0; j < 8; ++j)
                tv[j] = Cs[(t8 + j) * 200 + hd * 3 + 2];
            *(uint4*)(Vtb + (bh * HD_ + hd) * T_ + tb + t8) = *(const uint4*)tv;
        }
    }
}

// ---------------------------------------------------------------------------
// Kernel 2: flash attention, 128-q-row tile, software-pipelined K/V staging
// (double LDS buffer, ONE barrier/kt, loads for kt+1 drain after compute kt).
// Flat grid bid = qt*32 + bh so XCD = bh%8: all q-tiles of a head share L2.
// ---------------------------------------------------------------------------
__global__ __launch_bounds__(256) void k_attn(const unsigned short* __restrict__ Q,
                                              const unsigned short* __restrict__ K,
                                              const unsigned short* __restrict__ Vt,
                                              const float* __restrict__ mask,
                                              const int* __restrict__ flags,
                                              float* __restrict__ out) {
    __shared__ __align__(16) unsigned short Ks[2][64 * 72];
    __shared__ __align__(16) unsigned short Vs[2][64 * 72];   // [dim][kv]
    __shared__ __align__(16) unsigned short Ps[4][16 * 72];

    const int tid = threadIdx.x;
    const int wave = tid >> 6, lane = tid & 63;
    const int quad = lane >> 4, l16 = lane & 15;
    const int bh = blockIdx.x & 31, b = bh >> 3, h = bh & 7;
    const int qt = blockIdx.x >> 5;      // 0..15
    const int q0 = qt * 128;

    bfrag qf[2][2];
#pragma unroll
    for (int g = 0; g < 2; ++g) {
        size_t qrow = ((size_t)bh * T_ + q0 + wave * 32 + g * 16 + l16) * HD_;
        qf[g][0] = *(const bfrag*)(Q + qrow + quad * 8);
        qf[g][1] = *(const bfrag*)(Q + qrow + 32 + quad * 8);
    }
    float lsum[2][4] = {{0.f,0.f,0.f,0.f},{0.f,0.f,0.f,0.f}};
    ffrag of[2][4];
#pragma unroll
    for (int g = 0; g < 2; ++g)
#pragma unroll
        for (int nb = 0; nb < 4; ++nb) of[g][nb] = (ffrag){0.f, 0.f, 0.f, 0.f};

    const int fbase0 = (b * 32 + qt * 2) * 32;
    const int fbase1 = (b * 32 + qt * 2 + 1) * 32;

    // staging geometry: chunk i covers row r=(tid+i*256)>>3, 16B col c=tid&7
    const int sr0 = tid >> 3, sr1 = (tid + 256) >> 3, sc = tid & 7;
    const unsigned short* Kbase = K  + (size_t)bh * T_ * HD_;
    const unsigned short* Vbase = Vt + (size_t)bh * HD_ * T_;

    uint4 kreg[2], vreg[2];
    // preload kt = 0
    kreg[0] = *(const uint4*)(Kbase + (size_t)sr0 * HD_ + sc * 8);
    kreg[1] = *(const uint4*)(Kbase + (size_t)sr1 * HD_ + sc * 8);
    vreg[0] = *(const uint4*)(Vbase + (size_t)sr0 * T_ + sc * 8);
    vreg[1] = *(const uint4*)(Vbase + (size_t)sr1 * T_ + sc * 8);
    *(uint4*)(&Ks[0][sr0 * 72 + sc * 8]) = kreg[0];
    *(uint4*)(&Ks[0][sr1 * 72 + sc * 8]) = kreg[1];
    *(uint4*)(&Vs[0][sr0 * 72 + sc * 8]) = vreg[0];
    *(uint4*)(&Vs[0][sr1 * 72 + sc * 8]) = vreg[1];
    __syncthreads();

    for (int kt = 0; kt < 32; ++kt) {
        const int cur = kt & 1;
        // issue loads for kt+1 (drain AFTER the compute below)
        if (kt < 31) {
            const int kn = (kt + 1) * 64;
            kreg[0] = *(const uint4*)(Kbase + (size_t)(kn + sr0) * HD_ + sc * 8);
            kreg[1] = *(const uint4*)(Kbase + (size_t)(kn + sr1) * HD_ + sc * 8);
            vreg[0] = *(const uint4*)(Vbase + (size_t)sr0 * T_ + kn + sc * 8);
            vreg[1] = *(const uint4*)(Vbase + (size_t)sr1 * T_ + kn + sc * 8);
        }
        int fl[2];
        fl[0] = flags[fbase0 + kt];
        fl[1] = flags[fbase1 + kt];

        // V fragments once per kt (shared by both row-groups)
        bfrag vf[2][4];
#pragma unroll
        for (int ks = 0; ks < 2; ++ks)
#pragma unroll
            for (int nb = 0; nb < 4; ++nb)
                vf[ks][nb] = *(const bfrag*)(&Vs[cur][(nb * 16 + l16) * 72 + (ks * 4 + quad) * 8]);

#pragma unroll
        for (int g = 0; g < 2; ++g) {
            // S = Q K^T (scale folded into Q)
            ffrag sf[4];
#pragma unroll
            for (int ns = 0; ns < 4; ++ns) {
                ffrag a = (ffrag){0.f, 0.f, 0.f, 0.f};
#pragma unroll
                for (int ks = 0; ks < 2; ++ks) {
                    bfrag kf = *(const bfrag*)(&Ks[cur][(ns * 16 + l16) * 72 + (ks * 4 + quad) * 8]);
                    a = __builtin_amdgcn_mfma_f32_16x16x32_bf16(qf[g][ks], kf, a, 0, 0, 0);
                }
                sf[ns] = a;
            }
            // p = exp2(s [+ (m-1)*1e4*log2e]); row-sum; P -> LDS (same-wave)
            if (fl[g]) {
#pragma unroll
                for (int reg = 0; reg < 4; ++reg) {
                    int tq = q0 + wave * 32 + g * 16 + quad * 4 + reg;
                    const float* mrow = mask + ((size_t)b * T_ + tq) * T_ + kt * 64;
#pragma unroll
                    for (int ns = 0; ns < 4; ++ns) {
                        float msk = mrow[ns * 16 + l16];
                        float p = __builtin_amdgcn_exp2f(
                            fmaf(msk, MASK_L2E, sf[ns][reg] - MASK_L2E));
                        lsum[g][reg] += p;
                        Ps[wave][(quad * 4 + reg) * 72 + ns * 16 + l16] = f2bf_fast(p);
                    }
                }
            } else {
#pragma unroll
                for (int reg = 0; reg < 4; ++reg) {
#pragma unroll
                    for (int ns = 0; ns < 4; ++ns) {
                        float p = __builtin_amdgcn_exp2f(sf[ns][reg]);
                        lsum[g][reg] += p;
                        Ps[wave][(quad * 4 + reg) * 72 + ns * 16 + l16] = f2bf_fast(p);
                    }
                }
            }
            // O_g += P_g V
#pragma unroll
            for (int ks = 0; ks < 2; ++ks) {
                bfrag pf = *(const bfrag*)(&Ps[wave][l16 * 72 + (ks * 4 + quad) * 8]);
#pragma unroll
                for (int nb = 0; nb < 4; ++nb)
                    of[g][nb] = __builtin_amdgcn_mfma_f32_16x16x32_bf16(pf, vf[ks][nb], of[g][nb], 0, 0, 0);
            }
        }
        // write staged kt+1 into the other buffer, then one barrier
        if (kt < 31) {
            const int nxt = cur ^ 1;
            *(uint4*)(&Ks[nxt][sr0 * 72 + sc * 8]) = kreg[0];
            *(uint4*)(&Ks[nxt][sr1 * 72 + sc * 8]) = kreg[1];
            *(uint4*)(&Vs[nxt][sr0 * 72 + sc * 8]) = vreg[0];
            *(uint4*)(&Vs[nxt][sr1 * 72 + sc * 8]) = vreg[1];
            __syncthreads();
        }
    }
    // epilogue: shuffle-reduce row-sums, normalize, fp32 store
#pragma unroll
    for (int g = 0; g < 2; ++g)
#pragma unroll
    for (int reg = 0; reg < 4; ++reg) {
        float s = lsum[g][reg];
#pragma unroll
        for (int d = 1; d < 16; d <<= 1) s += __shfl_xor(s, d, 64);
        float inv = 1.0f / s;
        int t = q0 + wave * 32 + g * 16 + quad * 4 + reg;
#pragma unroll
        for (int nb = 0; nb < 4; ++nb)
            out[((size_t)b * T_ + t) * DM_ + h * 64 + nb * 16 + l16] = of[g][nb][reg] * inv;
    }
}

// ---------------------------------------------------------------------------
extern "C" void kernel_launch(void* const* d_in, const int* in_sizes, int n_in,
                              void* d_out, int out_size, void* d_ws, size_t ws_size,
                              hipStream_t stream) {
    const float* X    = (const float*)d_in[0];   // [4,2048,512] fp32
    const float* mask = (const float*)d_in[1];   // [4,1,2048,2048] fp32
    const float* W    = (const float*)d_in[2];   // [512,1536] fp32
    const float* bias = (const float*)d_in[3];   // [1536] fp32
    float* outp = (float*)d_out;                 // [4,2048,512] fp32

    char* ws = (char*)d_ws;
    unsigned short* Wt  = (unsigned short*)(ws);              // 1.5 MB
    unsigned short* Xb  = (unsigned short*)(ws + 1572864);    // 8 MB
    unsigned short* Qb  = (unsigned short*)(ws + 9961472);    // 8 MB
    unsigned short* Kb  = (unsigned short*)(ws + 18350080);   // 8 MB
    unsigned short* Vtb = (unsigned short*)(ws + 26738688);   // 8 MB
    int*            flg = (int*)(ws + 35127296);              // 16 KB (end ~35.1 MB)

    hipMemsetAsync(flg, 0, 16384, stream);
    k_prep     <<<dim3(960), 256, 0, stream>>>(W, X, mask, Wt, Xb, flg);
    k_gemm_qkv <<<dim3(512), 256, 0, stream>>>(Xb, Wt, bias, Qb, Kb, Vtb);
    k_attn     <<<dim3(512), 256, 0, stream>>>(Qb, Kb, Vtb, mask, flg, outp);
}